// Round 1
// baseline (1812.008 us; speedup 1.0000x reference)
//
#include <hip/hip_runtime.h>

// DCCF encoder: U=100000 users, I=50000 items, D=64, K=128, L=2, E=1250000
// N = 150000 nodes. All f32.
//
// d_out layout (float): [final NxD][gnn LxNxD][intl LxNxD][gaa LxNxD][iaa LxNxD]
// (ua=final[:U], ia=final[U:] are contiguous => final written directly.)
//
// Strategy:
//  - Build CSR once per launch (hist/scan/scatter) -> t_sorted, v_sorted.
//    Adjacency is layer-invariant, so all SpMMs become per-node gather loops
//    (no E*D scatter atomics).
//  - D=64 == wavefront: one wave per node, lane = feature dim. Row gathers are
//    single coalesced 256B loads; dot products are shfl_xor butterflies.
//  - adaptive_vals: d_inv factors out of the spmm => single fused pass per node
//    computes alphas, row sums, and the alpha-weighted ek accumulation (no
//    alpha materialization, no second edge loop).
//  - intent (softmax(ek@W)@W^T): W staged in LDS padded to 129 floats/row ->
//    conflict-free in both access phases; one wave per node.

#define U_CNT 100000
#define I_CNT 50000
#define D_DIM 64
#define K_DIM 128
#define L_LAYERS 2
#define E_CNT 1250000
#define N_CNT (U_CNT + I_CNT)
#define EPSF 1e-12f

__device__ __forceinline__ float wave_sum(float v) {
#pragma unroll
  for (int off = 32; off > 0; off >>= 1) v += __shfl_xor(v, off, 64);
  return v;
}
__device__ __forceinline__ float wave_max(float v) {
#pragma unroll
  for (int off = 32; off > 0; off >>= 1) v = fmaxf(v, __shfl_xor(v, off, 64));
  return v;
}

__global__ void init_kernel(const float* __restrict__ ue, const float* __restrict__ ie,
                            float* __restrict__ ek, float* __restrict__ fin) {
  int idx = blockIdx.x * blockDim.x + threadIdx.x;
  const int total = N_CNT * D_DIM;
  for (; idx < total; idx += gridDim.x * blockDim.x) {
    float v = (idx < U_CNT * D_DIM) ? ue[idx] : ie[idx - U_CNT * D_DIM];
    ek[idx] = v;
    fin[idx] = v;  // final = all_emb[0] + sum of later ek's
  }
}

__global__ void hist_kernel(const int* __restrict__ h_idx, int* __restrict__ counts) {
  int e = blockIdx.x * blockDim.x + threadIdx.x;
  for (; e < E_CNT; e += gridDim.x * blockDim.x) atomicAdd(&counts[h_idx[e]], 1);
}

// single-block exclusive scan of counts[N] -> row_ptr[N+1], cursor copy
__global__ void scan_kernel(const int* __restrict__ counts, int* __restrict__ row_ptr,
                            int* __restrict__ cursor) {
  __shared__ int wsum[16];
  __shared__ int s_carry, s_total;
  int tid = threadIdx.x, lane = tid & 63, wv = tid >> 6;
  if (tid == 0) s_carry = 0;
  __syncthreads();
  for (int base = 0; base < N_CNT; base += 4096) {
    int idx = base + tid * 4;
    int v0 = (idx + 0 < N_CNT) ? counts[idx + 0] : 0;
    int v1 = (idx + 1 < N_CNT) ? counts[idx + 1] : 0;
    int v2 = (idx + 2 < N_CNT) ? counts[idx + 2] : 0;
    int v3 = (idx + 3 < N_CNT) ? counts[idx + 3] : 0;
    int s = v0 + v1 + v2 + v3;
    int x = s;
#pragma unroll
    for (int off = 1; off < 64; off <<= 1) {
      int y = __shfl_up(x, off, 64);
      if (lane >= off) x += y;
    }
    if (lane == 63) wsum[wv] = x;
    __syncthreads();
    if (wv == 0 && lane < 16) {
      int w = wsum[lane];
      int xx = w;
#pragma unroll
      for (int off = 1; off < 16; off <<= 1) {
        int y = __shfl_up(xx, off, 64);
        if (lane >= off) xx += y;
      }
      wsum[lane] = xx - w;  // exclusive wave offset
      if (lane == 15) s_total = xx;
    }
    __syncthreads();
    int carry = s_carry;
    int e0 = carry + wsum[wv] + (x - s);
    int e1 = e0 + v0, e2 = e1 + v1, e3 = e2 + v2;
    if (idx + 0 < N_CNT) { row_ptr[idx + 0] = e0; cursor[idx + 0] = e0; }
    if (idx + 1 < N_CNT) { row_ptr[idx + 1] = e1; cursor[idx + 1] = e1; }
    if (idx + 2 < N_CNT) { row_ptr[idx + 2] = e2; cursor[idx + 2] = e2; }
    if (idx + 3 < N_CNT) { row_ptr[idx + 3] = e3; cursor[idx + 3] = e3; }
    __syncthreads();
    if (tid == 0) s_carry = carry + s_total;
    __syncthreads();
  }
  if (threadIdx.x == 0) row_ptr[N_CNT] = s_carry;
}

__global__ void scatter_kernel(const int* __restrict__ h_idx, const int* __restrict__ t_idx,
                               const float* __restrict__ adj_vals, int* __restrict__ cursor,
                               int* __restrict__ t_sorted, float* __restrict__ v_sorted) {
  int e = blockIdx.x * blockDim.x + threadIdx.x;
  for (; e < E_CNT; e += gridDim.x * blockDim.x) {
    int h = h_idx[e];
    int pos = atomicAdd(&cursor[h], 1);
    t_sorted[pos] = t_idx[e];
    v_sorted[pos] = adj_vals[e];
  }
}

// gnn = spmm(adj_vals, ek); also per-node inverse L2 norm of gnn row
__global__ void spmm_gnn_kernel(const float* __restrict__ ek, const int* __restrict__ t_sorted,
                                const float* __restrict__ v_sorted,
                                const int* __restrict__ row_ptr, float* __restrict__ gnn,
                                float* __restrict__ invn_g) {
  int wv = threadIdx.x >> 6, lane = threadIdx.x & 63;
  int n = blockIdx.x * 4 + wv;
  if (n >= N_CNT) return;
  int start = row_ptr[n], end = row_ptr[n + 1];
  float acc = 0.f;
  int i = start;
  for (; i + 1 < end; i += 2) {
    int t0 = t_sorted[i], t1 = t_sorted[i + 1];
    float v0 = v_sorted[i], v1 = v_sorted[i + 1];
    float x0 = ek[(size_t)t0 * D_DIM + lane];
    float x1 = ek[(size_t)t1 * D_DIM + lane];
    acc = fmaf(v0, x0, acc);
    acc = fmaf(v1, x1, acc);
  }
  if (i < end) acc = fmaf(v_sorted[i], ek[(size_t)t_sorted[i] * D_DIM + lane], acc);
  gnn[(size_t)n * D_DIM + lane] = acc;
  float s = wave_sum(acc * acc);
  if (lane == 0) invn_g[n] = 1.f / fmaxf(sqrtf(s), EPSF);
}

// intl rows for nodes [node_off, node_off+count): softmax(ek_row @ W) @ W^T
__global__ void intent_kernel(const float* __restrict__ ek, const float* __restrict__ W,
                              int node_off, int count, float* __restrict__ intl,
                              float* __restrict__ invn_i) {
  __shared__ float Ws[D_DIM * (K_DIM + 1)];
  __shared__ float es[4 * D_DIM];
  __shared__ float ps[4 * K_DIM];
  int tid = threadIdx.x, lane = tid & 63, wv = tid >> 6;
  for (int idx = tid; idx < D_DIM * K_DIM; idx += blockDim.x) {
    int d = idx >> 7, k = idx & 127;
    Ws[d * (K_DIM + 1) + k] = W[idx];
  }
  __syncthreads();
  int nl = blockIdx.x * 4 + wv;
  if (nl >= count) return;
  int node = node_off + nl;
  float e = ek[(size_t)node * D_DIM + lane];
  es[wv * D_DIM + lane] = e;
  float a0 = 0.f, a1 = 0.f;
#pragma unroll 8
  for (int d = 0; d < D_DIM; d++) {
    float ed = es[wv * D_DIM + d];  // broadcast
    a0 = fmaf(ed, Ws[d * (K_DIM + 1) + lane], a0);
    a1 = fmaf(ed, Ws[d * (K_DIM + 1) + 64 + lane], a1);
  }
  float m = wave_max(fmaxf(a0, a1));
  float p0 = __expf(a0 - m), p1 = __expf(a1 - m);
  float s = wave_sum(p0 + p1);
  float inv_s = 1.f / s;
  p0 *= inv_s;
  p1 *= inv_s;
  ps[wv * K_DIM + lane] = p0;
  ps[wv * K_DIM + 64 + lane] = p1;
  float acc = 0.f;
#pragma unroll 8
  for (int k = 0; k < K_DIM; k++) {
    // bank = (lane*129 + k) % 32 = (lane + k) % 32 -> conflict-free (2-way aliasing is free)
    acc = fmaf(ps[wv * K_DIM + k], Ws[lane * (K_DIM + 1) + k], acc);
  }
  intl[(size_t)node * D_DIM + lane] = acc;
  float ns = wave_sum(acc * acc);
  if (lane == 0) invn_i[node] = 1.f / fmaxf(sqrtf(ns), EPSF);
}

// Fused: per-node edge loop computing both adaptive alphas, row sums, and the
// alpha-weighted ek accumulation (d_inv factored out), then gaa/iaa, next ek,
// and the running `final` accumulation.
__global__ void passB_kernel(const float* __restrict__ ek, const float* __restrict__ gnn,
                             const float* __restrict__ intl, const float* __restrict__ invn_g,
                             const float* __restrict__ invn_i, const int* __restrict__ t_sorted,
                             const int* __restrict__ row_ptr, float* __restrict__ gaa,
                             float* __restrict__ iaa, float* __restrict__ ek_next,
                             float* __restrict__ fin) {
  int wv = threadIdx.x >> 6, lane = threadIdx.x & 63;
  int n = blockIdx.x * 4 + wv;
  if (n >= N_CNT) return;
  int start = row_ptr[n], end = row_ptr[n + 1];
  float g_h = gnn[(size_t)n * D_DIM + lane];
  float i_h = intl[(size_t)n * D_DIM + lane];
  float ig = invn_g[n], ii = invn_i[n];
  float rs_g = 0.f, rs_i = 0.f;
  float acc_g = 0.f, acc_i = 0.f;
  for (int i = start; i < end; i++) {
    int t = t_sorted[i];
    float gt = gnn[(size_t)t * D_DIM + lane];
    float it = intl[(size_t)t * D_DIM + lane];
    float ekt = ek[(size_t)t * D_DIM + lane];
    float ivgt = invn_g[t];
    float ivit = invn_i[t];
    float dg = wave_sum(g_h * gt);
    float di = wave_sum(i_h * it);
    float ag = fmaf(dg * ig, ivgt, 1.f) * 0.5f;
    float ai = fmaf(di * ii, ivit, 1.f) * 0.5f;
    rs_g += ag;
    rs_i += ai;
    acc_g = fmaf(ag, ekt, acc_g);
    acc_i = fmaf(ai, ekt, acc_i);
  }
  float dg_inv = (rs_g > 0.f) ? 1.f / rs_g : 0.f;
  float di_inv = (rs_i > 0.f) ? 1.f / rs_i : 0.f;
  acc_g *= dg_inv;
  acc_i *= di_inv;
  gaa[(size_t)n * D_DIM + lane] = acc_g;
  iaa[(size_t)n * D_DIM + lane] = acc_i;
  float ekh = ek[(size_t)n * D_DIM + lane];
  float en = g_h + i_h + acc_g + acc_i + ekh;
  ek_next[(size_t)n * D_DIM + lane] = en;
  fin[(size_t)n * D_DIM + lane] += en;
}

extern "C" void kernel_launch(void* const* d_in, const int* in_sizes, int n_in, void* d_out,
                              int out_size, void* d_ws, size_t ws_size, hipStream_t stream) {
  const float* user_emb = (const float*)d_in[0];
  const float* item_emb = (const float*)d_in[1];
  const float* user_intent = (const float*)d_in[2];
  const float* item_intent = (const float*)d_in[3];
  const float* adj_vals = (const float*)d_in[4];
  const int* h_idx = (const int*)d_in[5];
  const int* t_idx = (const int*)d_in[6];
  // d_in[7]=users, d_in[8]=items: unused by the reference computation.

  float* out = (float*)d_out;
  float* fin = out;  // N*D  (ua || ia)
  float* gnn_base = out + (size_t)N_CNT * D_DIM;
  float* intl_base = gnn_base + (size_t)L_LAYERS * N_CNT * D_DIM;
  float* gaa_base = intl_base + (size_t)L_LAYERS * N_CNT * D_DIM;
  float* iaa_base = gaa_base + (size_t)L_LAYERS * N_CNT * D_DIM;

  float* ws = (float*)d_ws;
  float* ekA = ws;                                   // N*D
  float* ekB = ekA + (size_t)N_CNT * D_DIM;          // N*D
  float* v_sorted = ekB + (size_t)N_CNT * D_DIM;     // E
  float* invn_g = v_sorted + E_CNT;                  // N
  float* invn_i = invn_g + N_CNT;                    // N
  int* t_sorted = (int*)(invn_i + N_CNT);            // E
  int* row_ptr = t_sorted + E_CNT;                   // N+1
  int* counts = row_ptr + (N_CNT + 1);               // N
  int* cursor = counts + N_CNT;                      // N

  hipMemsetAsync(counts, 0, N_CNT * sizeof(int), stream);
  init_kernel<<<2048, 256, 0, stream>>>(user_emb, item_emb, ekA, fin);
  hist_kernel<<<2048, 256, 0, stream>>>(h_idx, counts);
  scan_kernel<<<1, 1024, 0, stream>>>(counts, row_ptr, cursor);
  scatter_kernel<<<2048, 256, 0, stream>>>(h_idx, t_idx, adj_vals, cursor, t_sorted, v_sorted);

  float* ek = ekA;
  float* ekn = ekB;
  const int nodeBlocks = (N_CNT + 3) / 4;
  for (int l = 0; l < L_LAYERS; l++) {
    float* gnn = gnn_base + (size_t)l * N_CNT * D_DIM;
    float* intl = intl_base + (size_t)l * N_CNT * D_DIM;
    float* gaa = gaa_base + (size_t)l * N_CNT * D_DIM;
    float* iaa = iaa_base + (size_t)l * N_CNT * D_DIM;
    spmm_gnn_kernel<<<nodeBlocks, 256, 0, stream>>>(ek, t_sorted, v_sorted, row_ptr, gnn, invn_g);
    intent_kernel<<<(U_CNT + 3) / 4, 256, 0, stream>>>(ek, user_intent, 0, U_CNT, intl, invn_i);
    intent_kernel<<<(I_CNT + 3) / 4, 256, 0, stream>>>(ek, item_intent, U_CNT, I_CNT, intl,
                                                       invn_i);
    passB_kernel<<<nodeBlocks, 256, 0, stream>>>(ek, gnn, intl, invn_g, invn_i, t_sorted, row_ptr,
                                                 gaa, iaa, ekn, fin);
    float* tmp = ek;
    ek = ekn;
    ekn = tmp;
  }
}

// Round 2
// 1619.147 us; speedup vs baseline: 1.1191x; 1.1191x over previous
//
#include <hip/hip_runtime.h>

// DCCF encoder: U=100000, I=50000, D=64, K=128, L=2, E=1250000, N=150000. f32.
//
// d_out layout (float): [final NxD][gnn LxNxD][intl LxNxD][gaa LxNxD][iaa LxNxD]
//
// R2 changes vs R1:
//  - passB / spmm edge loops restructured: wave = node, lane = (slot 0..3, 16
//    lanes x float4). 4 edges in flight per iteration, 12 outstanding dwordx4
//    gathers, 4-step segmented shuffle dots (was 1 edge / 3 loads / 6-step).
//  - intent: single merged kernel (U%4==0 so blocks never straddle), paired
//    LDS layout (W[d][k],W[d][k+64] adjacent) -> all reads are ds_read_b64,
//    2-way bank aliasing only (free); broadcasts via v_readlane not LDS.

#define U_CNT 100000
#define I_CNT 50000
#define D_DIM 64
#define K_DIM 128
#define L_LAYERS 2
#define E_CNT 1250000
#define N_CNT (U_CNT + I_CNT)
#define EPSF 1e-12f

__device__ __forceinline__ float wave_sum(float v) {
#pragma unroll
  for (int off = 32; off > 0; off >>= 1) v += __shfl_xor(v, off, 64);
  return v;
}
__device__ __forceinline__ float wave_max(float v) {
#pragma unroll
  for (int off = 32; off > 0; off >>= 1) v = fmaxf(v, __shfl_xor(v, off, 64));
  return v;
}
__device__ __forceinline__ float bcast(float v, int l) {
  return __int_as_float(__builtin_amdgcn_readlane(__float_as_int(v), l));
}

__global__ void init_kernel(const float* __restrict__ ue, const float* __restrict__ ie,
                            float* __restrict__ ek, float* __restrict__ fin) {
  int idx = blockIdx.x * blockDim.x + threadIdx.x;
  const int total = N_CNT * D_DIM;
  for (; idx < total; idx += gridDim.x * blockDim.x) {
    float v = (idx < U_CNT * D_DIM) ? ue[idx] : ie[idx - U_CNT * D_DIM];
    ek[idx] = v;
    fin[idx] = v;
  }
}

__global__ void hist_kernel(const int* __restrict__ h_idx, int* __restrict__ counts) {
  int e = blockIdx.x * blockDim.x + threadIdx.x;
  for (; e < E_CNT; e += gridDim.x * blockDim.x) atomicAdd(&counts[h_idx[e]], 1);
}

__global__ void scan_kernel(const int* __restrict__ counts, int* __restrict__ row_ptr,
                            int* __restrict__ cursor) {
  __shared__ int wsum[16];
  __shared__ int s_carry, s_total;
  int tid = threadIdx.x, lane = tid & 63, wv = tid >> 6;
  if (tid == 0) s_carry = 0;
  __syncthreads();
  for (int base = 0; base < N_CNT; base += 4096) {
    int idx = base + tid * 4;
    int v0 = (idx + 0 < N_CNT) ? counts[idx + 0] : 0;
    int v1 = (idx + 1 < N_CNT) ? counts[idx + 1] : 0;
    int v2 = (idx + 2 < N_CNT) ? counts[idx + 2] : 0;
    int v3 = (idx + 3 < N_CNT) ? counts[idx + 3] : 0;
    int s = v0 + v1 + v2 + v3;
    int x = s;
#pragma unroll
    for (int off = 1; off < 64; off <<= 1) {
      int y = __shfl_up(x, off, 64);
      if (lane >= off) x += y;
    }
    if (lane == 63) wsum[wv] = x;
    __syncthreads();
    if (wv == 0 && lane < 16) {
      int w = wsum[lane];
      int xx = w;
#pragma unroll
      for (int off = 1; off < 16; off <<= 1) {
        int y = __shfl_up(xx, off, 64);
        if (lane >= off) xx += y;
      }
      wsum[lane] = xx - w;
      if (lane == 15) s_total = xx;
    }
    __syncthreads();
    int carry = s_carry;
    int e0 = carry + wsum[wv] + (x - s);
    int e1 = e0 + v0, e2 = e1 + v1, e3 = e2 + v2;
    if (idx + 0 < N_CNT) { row_ptr[idx + 0] = e0; cursor[idx + 0] = e0; }
    if (idx + 1 < N_CNT) { row_ptr[idx + 1] = e1; cursor[idx + 1] = e1; }
    if (idx + 2 < N_CNT) { row_ptr[idx + 2] = e2; cursor[idx + 2] = e2; }
    if (idx + 3 < N_CNT) { row_ptr[idx + 3] = e3; cursor[idx + 3] = e3; }
    __syncthreads();
    if (tid == 0) s_carry = carry + s_total;
    __syncthreads();
  }
  if (threadIdx.x == 0) row_ptr[N_CNT] = s_carry;
}

__global__ void scatter_kernel(const int* __restrict__ h_idx, const int* __restrict__ t_idx,
                               const float* __restrict__ adj_vals, int* __restrict__ cursor,
                               int* __restrict__ t_sorted, float* __restrict__ v_sorted) {
  int e = blockIdx.x * blockDim.x + threadIdx.x;
  for (; e < E_CNT; e += gridDim.x * blockDim.x) {
    int h = h_idx[e];
    int pos = atomicAdd(&cursor[h], 1);
    t_sorted[pos] = t_idx[e];
    v_sorted[pos] = adj_vals[e];
  }
}

// gnn = spmm(adj_vals, ek), 4 edges/iter, float4 lanes; also 1/||gnn row||
__global__ void spmm_gnn_kernel(const float* __restrict__ ek, const int* __restrict__ t_sorted,
                                const float* __restrict__ v_sorted,
                                const int* __restrict__ row_ptr, float* __restrict__ gnn,
                                float* __restrict__ invn_g) {
  int wv = threadIdx.x >> 6, lane = threadIdx.x & 63;
  int slot = lane >> 4, f = (lane & 15) << 2;
  int n = blockIdx.x * 4 + wv;
  if (n >= N_CNT) return;
  int start = row_ptr[n], end = row_ptr[n + 1];
  float ax = 0.f, ay = 0.f, az = 0.f, aw = 0.f;
  for (int i = start; i < end; i += 4) {
    int idx = i + slot;
    int ic = (idx < end) ? idx : (end - 1);
    int t = t_sorted[ic];
    float v = v_sorted[ic];
    if (idx >= end) v = 0.f;
    const float4 x = *(const float4*)(ek + (size_t)t * D_DIM + f);
    ax = fmaf(v, x.x, ax);
    ay = fmaf(v, x.y, ay);
    az = fmaf(v, x.z, az);
    aw = fmaf(v, x.w, aw);
  }
#pragma unroll
  for (int off = 16; off <= 32; off <<= 1) {
    ax += __shfl_xor(ax, off, 64);
    ay += __shfl_xor(ay, off, 64);
    az += __shfl_xor(az, off, 64);
    aw += __shfl_xor(aw, off, 64);
  }
  if (slot == 0) {
    float4 o = make_float4(ax, ay, az, aw);
    *(float4*)(gnn + (size_t)n * D_DIM + f) = o;
  }
  float ss = ax * ax + ay * ay + az * az + aw * aw;
#pragma unroll
  for (int off = 1; off <= 8; off <<= 1) ss += __shfl_xor(ss, off, 64);
  if (lane == 0) invn_g[n] = 1.f / fmaxf(sqrtf(ss), EPSF);
}

// intl = softmax(ek @ W) @ W^T for all N nodes (W chosen per side; U%4==0 so
// each block is single-sided). Paired LDS layout: Wp[d*130+2k']=W[d][k'],
// Wp[d*130+2k'+1]=W[d][k'+64] -> every access is a b64 read, <=2-way aliasing.
__global__ void intent_kernel(const float* __restrict__ ek, const float* __restrict__ Wu,
                              const float* __restrict__ Wi, float* __restrict__ intl,
                              float* __restrict__ invn_i) {
  __shared__ float Wp[D_DIM * 130];
  int tid = threadIdx.x, lane = tid & 63, wv = tid >> 6;
  int n0 = blockIdx.x * 4;
  const float* __restrict__ W = (n0 < U_CNT) ? Wu : Wi;
  for (int idx = tid; idx < D_DIM * K_DIM; idx += blockDim.x) {
    int d = idx >> 7, k = idx & 127;
    int kp = (k < 64) ? (2 * k) : (2 * (k - 64) + 1);
    Wp[d * 130 + kp] = W[idx];
  }
  __syncthreads();
  int n = n0 + wv;
  float e = ek[(size_t)n * D_DIM + lane];
  float a0 = 0.f, a1 = 0.f;
#pragma unroll
  for (int d = 0; d < D_DIM; d++) {
    float ed = bcast(e, d);
    const float2 w = *(const float2*)(Wp + d * 130 + 2 * lane);
    a0 = fmaf(ed, w.x, a0);
    a1 = fmaf(ed, w.y, a1);
  }
  float m = wave_max(fmaxf(a0, a1));
  float p0 = __expf(a0 - m), p1 = __expf(a1 - m);
  float s = wave_sum(p0 + p1);
  float inv_s = 1.f / s;
  p0 *= inv_s;
  p1 *= inv_s;
  float acc = 0.f;
#pragma unroll
  for (int k = 0; k < 64; k++) {
    float pk0 = bcast(p0, k), pk1 = bcast(p1, k);
    const float2 w = *(const float2*)(Wp + lane * 130 + 2 * k);
    acc = fmaf(pk0, w.x, acc);
    acc = fmaf(pk1, w.y, acc);
  }
  intl[(size_t)n * D_DIM + lane] = acc;
  float ns = wave_sum(acc * acc);
  if (lane == 0) invn_i[n] = 1.f / fmaxf(sqrtf(ns), EPSF);
}

// Fused adaptive pass: 4 edges/iter, float4 lanes. Computes both alphas, row
// sums, alpha-weighted ek accum (d_inv factored out), gaa/iaa, next ek, final.
__global__ void passB_kernel(const float* __restrict__ ek, const float* __restrict__ gnn,
                             const float* __restrict__ intl, const float* __restrict__ invn_g,
                             const float* __restrict__ invn_i, const int* __restrict__ t_sorted,
                             const int* __restrict__ row_ptr, float* __restrict__ gaa,
                             float* __restrict__ iaa, float* __restrict__ ek_next,
                             float* __restrict__ fin) {
  int wv = threadIdx.x >> 6, lane = threadIdx.x & 63;
  int slot = lane >> 4, f = (lane & 15) << 2;
  int n = blockIdx.x * 4 + wv;
  if (n >= N_CNT) return;
  int start = row_ptr[n], end = row_ptr[n + 1];
  const float4 gh = *(const float4*)(gnn + (size_t)n * D_DIM + f);
  const float4 ih = *(const float4*)(intl + (size_t)n * D_DIM + f);
  float ig = invn_g[n], ii = invn_i[n];
  float rs_g = 0.f, rs_i = 0.f;
  float gx = 0.f, gy = 0.f, gz = 0.f, gw = 0.f;
  float ix = 0.f, iy = 0.f, iz = 0.f, iw = 0.f;
  for (int i = start; i < end; i += 4) {
    int idx = i + slot;
    int ic = (idx < end) ? idx : (end - 1);
    int t = t_sorted[ic];
    size_t rb = (size_t)t * D_DIM + f;
    const float4 gt = *(const float4*)(gnn + rb);
    const float4 it = *(const float4*)(intl + rb);
    const float4 et = *(const float4*)(ek + rb);
    float ivg = invn_g[t];
    float ivi = invn_i[t];
    float dg = gh.x * gt.x + gh.y * gt.y + gh.z * gt.z + gh.w * gt.w;
    float di = ih.x * it.x + ih.y * it.y + ih.z * it.z + ih.w * it.w;
#pragma unroll
    for (int off = 1; off <= 8; off <<= 1) {
      dg += __shfl_xor(dg, off, 64);
      di += __shfl_xor(di, off, 64);
    }
    float ag = fmaf(dg * ig, ivg, 1.f) * 0.5f;
    float ai = fmaf(di * ii, ivi, 1.f) * 0.5f;
    if (idx >= end) { ag = 0.f; ai = 0.f; }
    rs_g += ag;
    rs_i += ai;
    gx = fmaf(ag, et.x, gx);
    gy = fmaf(ag, et.y, gy);
    gz = fmaf(ag, et.z, gz);
    gw = fmaf(ag, et.w, gw);
    ix = fmaf(ai, et.x, ix);
    iy = fmaf(ai, et.y, iy);
    iz = fmaf(ai, et.z, iz);
    iw = fmaf(ai, et.w, iw);
  }
#pragma unroll
  for (int off = 16; off <= 32; off <<= 1) {
    rs_g += __shfl_xor(rs_g, off, 64);
    rs_i += __shfl_xor(rs_i, off, 64);
    gx += __shfl_xor(gx, off, 64);
    gy += __shfl_xor(gy, off, 64);
    gz += __shfl_xor(gz, off, 64);
    gw += __shfl_xor(gw, off, 64);
    ix += __shfl_xor(ix, off, 64);
    iy += __shfl_xor(iy, off, 64);
    iz += __shfl_xor(iz, off, 64);
    iw += __shfl_xor(iw, off, 64);
  }
  float dgi = (rs_g > 0.f) ? 1.f / rs_g : 0.f;
  float dii = (rs_i > 0.f) ? 1.f / rs_i : 0.f;
  if (slot == 0) {
    size_t ob = (size_t)n * D_DIM + f;
    float4 ga = make_float4(gx * dgi, gy * dgi, gz * dgi, gw * dgi);
    float4 ia = make_float4(ix * dii, iy * dii, iz * dii, iw * dii);
    *(float4*)(gaa + ob) = ga;
    *(float4*)(iaa + ob) = ia;
    const float4 eh = *(const float4*)(ek + ob);
    float4 en = make_float4(gh.x + ih.x + ga.x + ia.x + eh.x, gh.y + ih.y + ga.y + ia.y + eh.y,
                            gh.z + ih.z + ga.z + ia.z + eh.z, gh.w + ih.w + ga.w + ia.w + eh.w);
    *(float4*)(ek_next + ob) = en;
    float4 fo = *(const float4*)(fin + ob);
    fo.x += en.x;
    fo.y += en.y;
    fo.z += en.z;
    fo.w += en.w;
    *(float4*)(fin + ob) = fo;
  }
}

extern "C" void kernel_launch(void* const* d_in, const int* in_sizes, int n_in, void* d_out,
                              int out_size, void* d_ws, size_t ws_size, hipStream_t stream) {
  const float* user_emb = (const float*)d_in[0];
  const float* item_emb = (const float*)d_in[1];
  const float* user_intent = (const float*)d_in[2];
  const float* item_intent = (const float*)d_in[3];
  const float* adj_vals = (const float*)d_in[4];
  const int* h_idx = (const int*)d_in[5];
  const int* t_idx = (const int*)d_in[6];

  float* out = (float*)d_out;
  float* fin = out;
  float* gnn_base = out + (size_t)N_CNT * D_DIM;
  float* intl_base = gnn_base + (size_t)L_LAYERS * N_CNT * D_DIM;
  float* gaa_base = intl_base + (size_t)L_LAYERS * N_CNT * D_DIM;
  float* iaa_base = gaa_base + (size_t)L_LAYERS * N_CNT * D_DIM;

  float* ws = (float*)d_ws;
  float* ekA = ws;                                // N*D
  float* ekB = ekA + (size_t)N_CNT * D_DIM;       // N*D
  float* v_sorted = ekB + (size_t)N_CNT * D_DIM;  // E
  float* invn_g = v_sorted + E_CNT;               // N
  float* invn_i = invn_g + N_CNT;                 // N
  int* t_sorted = (int*)(invn_i + N_CNT);         // E
  int* row_ptr = t_sorted + E_CNT;                // N+1
  int* counts = row_ptr + (N_CNT + 1);            // N
  int* cursor = counts + N_CNT;                   // N

  hipMemsetAsync(counts, 0, N_CNT * sizeof(int), stream);
  init_kernel<<<2048, 256, 0, stream>>>(user_emb, item_emb, ekA, fin);
  hist_kernel<<<2048, 256, 0, stream>>>(h_idx, counts);
  scan_kernel<<<1, 1024, 0, stream>>>(counts, row_ptr, cursor);
  scatter_kernel<<<2048, 256, 0, stream>>>(h_idx, t_idx, adj_vals, cursor, t_sorted, v_sorted);

  float* ek = ekA;
  float* ekn = ekB;
  const int nodeBlocks = (N_CNT + 3) / 4;
  for (int l = 0; l < L_LAYERS; l++) {
    float* gnn = gnn_base + (size_t)l * N_CNT * D_DIM;
    float* intl = intl_base + (size_t)l * N_CNT * D_DIM;
    float* gaa = gaa_base + (size_t)l * N_CNT * D_DIM;
    float* iaa = iaa_base + (size_t)l * N_CNT * D_DIM;
    spmm_gnn_kernel<<<nodeBlocks, 256, 0, stream>>>(ek, t_sorted, v_sorted, row_ptr, gnn, invn_g);
    intent_kernel<<<nodeBlocks, 256, 0, stream>>>(ek, user_intent, item_intent, intl, invn_i);
    passB_kernel<<<nodeBlocks, 256, 0, stream>>>(ek, gnn, intl, invn_g, invn_i, t_sorted, row_ptr,
                                                 gaa, iaa, ekn, fin);
    float* tmp = ek;
    ek = ekn;
    ekn = tmp;
  }
}